// Round 6
// baseline (1213.828 us; speedup 1.0000x reference)
//
#include <hip/hip_runtime.h>
#include <hip/hip_bf16.h>
#include <math.h>

typedef unsigned short u16;
typedef unsigned int   u32;
typedef __bf16 bf16x8 __attribute__((ext_vector_type(8)));
typedef u16    u16x8  __attribute__((ext_vector_type(8)));
typedef float  f32x4  __attribute__((ext_vector_type(4)));

#define B_  8
#define L_  4096
#define H_  256
#define P_  512
#define NC_ 32
#define CH_ 128

__device__ __forceinline__ float bf2f(u16 v) { return __uint_as_float(((u32)v) << 16); }
__device__ __forceinline__ u16 f2bf(float f) {
  u32 u = __float_as_uint(f);
  u32 r = u + 0x7FFFu + ((u >> 16) & 1u);
  return (u16)(r >> 16);
}

// async global->LDS, 16B per lane; LDS dest = wave-uniform base + lane*16
__device__ __forceinline__ void gload16(const u16* g, u16* l) {
  __builtin_amdgcn_global_load_lds((const __attribute__((address_space(1))) u32*)g,
                                   (__attribute__((address_space(3))) u32*)l, 16, 0, 0);
}

// ------------------------------------------------------- fp32 -> bf16 (x10)
struct F2B10 { const float* s[10]; };
__global__ __launch_bounds__(256) void k_f2b10(F2B10 a, u16* __restrict__ dst) {
  int g = blockIdx.y;
  int i = (blockIdx.x << 8) + threadIdx.x;
  dst[(size_t)g * 262144 + i] = f2bf(a.s[g][i]);
}

// ---------------------------------------------------------------- adaLN mods
__global__ __launch_bounds__(256) void k_mods(const float* __restrict__ cond,
                                              const float* __restrict__ wada,
                                              const float* __restrict__ bada,
                                              float* __restrict__ mods) {
  __shared__ float s[256];
  int b = blockIdx.y;
  int j = (blockIdx.x << 8) + threadIdx.x;
  float c = cond[b * 256 + threadIdx.x];
  s[threadIdx.x] = c / (1.0f + expf(-c));
  __syncthreads();
  float acc = bada[j];
  const float* wr = wada + (size_t)j * 256;
#pragma unroll 8
  for (int k = 0; k < 256; ++k) acc += s[k] * wr[k];
  mods[b * 3072 + j] = acc;
}

// ------------------------------------------------------------- transposes
__global__ __launch_bounds__(256) void k_tin2(const float* __restrict__ inP,
                                              const float* __restrict__ inT,
                                              u16* __restrict__ Pt, u16* __restrict__ Tt,
                                              int b0, int nb) {
  __shared__ u16 tile[64][65];
  int z = blockIdx.z;
  int sel = (z >= nb);
  int b = sel ? z - nb : z;
  const float* in = sel ? inT : inP;
  u16* out = sel ? Tt : Pt;
  int l0 = blockIdx.x << 6, h0 = blockIdx.y << 6;
  int tx = threadIdx.x, ty = threadIdx.y;
#pragma unroll
  for (int i = 0; i < 16; ++i) {
    int h = h0 + ty + i * 4;
    tile[ty + i * 4][tx] = f2bf(in[((size_t)(b0 + b) * 256 + h) * 4096 + l0 + tx]);
  }
  __syncthreads();
#pragma unroll
  for (int i = 0; i < 16; ++i) {
    int l = l0 + ty + i * 4;
    out[((size_t)b * 4096 + l) * 256 + h0 + tx] = tile[tx][ty + i * 4];
  }
}
__global__ __launch_bounds__(256) void k_tout(const u16* __restrict__ src, float* __restrict__ dst) {
  __shared__ u16 tile[64][65];
  int b = blockIdx.z, l0 = blockIdx.x << 6, h0 = blockIdx.y << 6;
  int tx = threadIdx.x, ty = threadIdx.y;
#pragma unroll
  for (int i = 0; i < 16; ++i) {
    int l = l0 + ty + i * 4;
    tile[ty + i * 4][tx] = src[((size_t)b * 4096 + l) * 256 + h0 + tx];
  }
  __syncthreads();
#pragma unroll
  for (int i = 0; i < 16; ++i) {
    int h = h0 + ty + i * 4;
    dst[((size_t)b * 256 + h) * 4096 + l0 + tx] = bf2f(tile[tx][ty + i * 4]);
  }
}

// ------------------------------------------------------------- LN + adaLN mod
__global__ __launch_bounds__(256) void k_lnmod(const u16* __restrict__ X, u16* __restrict__ U,
                                               const float* __restrict__ mods,
                                               int sh_off, int sc_off, int b0) {
  int t = blockIdx.x, tid = threadIdx.x;
  int b = b0 + (t >> 12);
  float x = bf2f(X[(size_t)t * 256 + tid]);
  float s1 = x, s2 = x * x;
#pragma unroll
  for (int off = 32; off; off >>= 1) { s1 += __shfl_xor(s1, off); s2 += __shfl_xor(s2, off); }
  __shared__ float red[8];
  int w = tid >> 6;
  if ((tid & 63) == 0) { red[w * 2] = s1; red[w * 2 + 1] = s2; }
  __syncthreads();
  s1 = red[0] + red[2] + red[4] + red[6];
  s2 = red[1] + red[3] + red[5] + red[7];
  float m = s1 * (1.0f / 256.0f);
  float v = fmaxf(s2 * (1.0f / 256.0f) - m * m, 0.0f);
  float r = rsqrtf(v + 1e-6f);
  float sc = mods[b * 3072 + sc_off + tid];
  float sh = mods[b * 3072 + sh_off + tid];
  U[(size_t)t * 256 + tid] = f2bf((x - m) * r * (1.0f + sc) + sh);
}

// ------------------------------------------------------------- S5 weight prep
__global__ __launch_bounds__(256) void k_wb2(const float* Lre0, const float* Lim0, const float* ls0,
                                             const float* Bre0, const float* Bim0, u16* WB0,
                                             const float* Lre1, const float* Lim1, const float* ls1,
                                             const float* Bre1, const float* Bim1, u16* WB1) {
  int s = blockIdx.y;
  const float* Lre = s ? Lre1 : Lre0;
  const float* Lim = s ? Lim1 : Lim0;
  const float* ls  = s ? ls1  : ls0;
  const float* Bre = s ? Bre1 : Bre0;
  const float* Bim = s ? Bim1 : Bim0;
  u16* WB = s ? WB1 : WB0;
  int p = blockIdx.x, h = threadIdx.x;
  float lre = Lre[p], lim = Lim[p];
  float dt = expf(ls[p]);
  float er = expf(lre * dt), sn, cs;
  sincosf(lim * dt, &sn, &cs);
  float ar = er * cs - 1.0f, ai = er * sn;
  float den = lre * lre + lim * lim;
  float cr = (ar * lre + ai * lim) / den;
  float ci = (ai * lre - ar * lim) / den;
  float br = Bre[p * 256 + h], bi = Bim[p * 256 + h];
  WB[(size_t)(2 * p) * 256 + h]     = f2bf(cr * br - ci * bi);
  WB[(size_t)(2 * p + 1) * 256 + h] = f2bf(cr * bi + ci * br);
}

// interleaved concat C-weight: K=2048, even k -> 2*Cre, odd -> -2*Cim
__global__ __launch_bounds__(256) void k_wc2(const float* Cre0, const float* Cim0, u16* W0,
                                             const float* Cre1, const float* Cim1, u16* W1) {
  int s = blockIdx.y;
  const float* Cre = s ? Cre1 : Cre0;
  const float* Cim = s ? Cim1 : Cim0;
  u16* W = s ? W1 : W0;
  int idx = (blockIdx.x << 8) + threadIdx.x;
  int h = idx >> 11, k = idx & 2047;
  int sc = ((k >> 10) << 9) + ((k & 1023) >> 1);
  float v = (k & 1) ? -2.0f * Cim[h * 1024 + sc] : 2.0f * Cre[h * 1024 + sc];
  W[idx] = f2bf(v);
}

// ------------------------------------------------------------- fused scans
__device__ __forceinline__ float2 lbar_of(const float* Lre, const float* Lim, const float* lstep,
                                          int p, float mul) {
  float dt = expf(lstep[p]) * mul;
  float er = expf(Lre[p] * dt), sn, cs;
  sincosf(Lim[p] * dt, &sn, &cs);
  return make_float2(er * cs, er * sn);
}

// one read of Bu -> BOTH direction chunk-carries (see round-5 comments)
__global__ __launch_bounds__(256) void k_scanA2(const float* Lre, const float* Lim, const float* lstep,
                                                const u16* __restrict__ Bu,
                                                float2* __restrict__ car_f, float2* __restrict__ car_b) {
  int g = (blockIdx.x << 8) + threadIdx.x;
  int p = g & 511, rb = (g >> 9) & 31, bl = g >> 14;
  float2 a = lbar_of(Lre, Lim, lstep, p, 1.0f);
  float fr = 0.f, fi = 0.f;
  float br_ = 0.f, bi_ = 0.f;
  float pr = 1.f, pi = 0.f;
  const u32* bup = (const u32*)Bu + (((size_t)((bl << 12) + rb * CH_)) << 9) + p;
#pragma unroll 4
  for (int j = 0; j < CH_; ++j) {
    u32 w = *bup;
    float er = bf2f((u16)(w & 0xFFFF)), ei = bf2f((u16)(w >> 16));
    float nr = a.x * fr - a.y * fi + er;
    float ni = a.x * fi + a.y * fr + ei;
    fr = nr; fi = ni;
    br_ += pr * er - pi * ei;
    bi_ += pr * ei + pi * er;
    float npr = pr * a.x - pi * a.y;
    float npi = pr * a.y + pi * a.x;
    pr = npr; pi = npi;
    bup += 512;
  }
  car_f[g] = make_float2(fr, fi);
  car_b[((size_t)bl << 14) + ((size_t)(31 - rb) << 9) + p] = make_float2(br_, bi_);
}

__global__ __launch_bounds__(256) void k_scanB2(const float* Lre, const float* Lim, const float* lstep,
                                                const float2* __restrict__ car_f,
                                                const float2* __restrict__ car_b,
                                                float2* __restrict__ cin_f, float2* __restrict__ cin_b) {
  int dir = blockIdx.y;
  int g = (blockIdx.x << 8) + threadIdx.x;
  int p = g & 511, bl = g >> 9;
  float2 an = lbar_of(Lre, Lim, lstep, p, (float)CH_);
  const float2* car = dir ? car_b : car_f;
  float2* cin = dir ? cin_b : cin_f;
  float xr = 0.f, xi = 0.f;
  size_t base = (size_t)bl * 16384 + p;
  for (int c = 0; c < NC_; ++c) {
    size_t src = base + (size_t)c * 512;
    size_t dst = dir ? (base + (size_t)(31 - c) * 512) : src;
    cin[dst] = make_float2(xr, xi);
    float2 E = car[src];
    float nr = an.x * xr - an.y * xi + E.x;
    float ni = an.x * xi + an.y * xr + E.y;
    xr = nr; xi = ni;
  }
}

// fwd pass: write packed xs -> xsf. bwd pass: overwrite Bu in place (race-free per thread).
__global__ __launch_bounds__(256) void k_scanC2(const float* Lre, const float* Lim, const float* lstep,
                                                u16* __restrict__ Bu,
                                                const float2* __restrict__ cin_f,
                                                const float2* __restrict__ cin_b,
                                                u32* __restrict__ xsf) {
  int g = (blockIdx.x << 8) + threadIdx.x;
  int p = g & 511, rb = (g >> 9) & 31, bl = g >> 14;
  float2 a = lbar_of(Lre, Lim, lstep, p, 1.0f);
  size_t rowbase = (((size_t)((bl << 12) + rb * CH_)) << 9) + p;
  const u32* bup = (const u32*)Bu + rowbase;
  u32* xop = xsf + rowbase;
  float2 c0 = cin_f[g];
  float xr = c0.x, xi = c0.y;
#pragma unroll 4
  for (int j = 0; j < CH_; ++j) {
    u32 w = *bup;
    float er = bf2f((u16)(w & 0xFFFF)), ei = bf2f((u16)(w >> 16));
    float nr = a.x * xr - a.y * xi + er;
    float ni = a.x * xi + a.y * xr + ei;
    xr = nr; xi = ni;
    *xop = (u32)f2bf(xr) | ((u32)f2bf(xi) << 16);
    bup += 512; xop += 512;
  }
  u32* bwp = (u32*)Bu + rowbase + ((size_t)(CH_ - 1) << 9);
  c0 = cin_b[g];
  xr = c0.x; xi = c0.y;
#pragma unroll 4
  for (int j = 0; j < CH_; ++j) {
    u32 w = *bwp;
    float er = bf2f((u16)(w & 0xFFFF)), ei = bf2f((u16)(w >> 16));
    float nr = a.x * xr - a.y * xi + er;
    float ni = a.x * xi + a.y * xr + ei;
    xr = nr; xi = ni;
    *bwp = (u32)f2bf(xr) | ((u32)f2bf(xi) << 16);
    bwp -= 512;
  }
}

// ------------------------------------------------------------- MFMA GEMM
// 512-thread, 8-wave, 64m x 256n tile. Whole N=256 in ONE n-block -> A panel
// read exactly once (no n-amplification); N=1024 uses 4 n-blocks (was 16).
// 2 blocks/CU (40 KB LDS) = 16 waves/CU. Both-sides XOR swizzle as before.
// MODE 0: bf16 store   1: gelu(acc+bias)   2: acc+bias   3: acc+bias+add
// MODE 4: acc+bias+res 5: res+g*(acc+bias) 6: cat S5 proj (A1|A2, K=2048)
template <int MODE>
__global__ __launch_bounds__(512, 4) void gemm256_bt(const u16* __restrict__ A, const u16* __restrict__ A2,
                                                     const u16* __restrict__ W, u16* __restrict__ out,
                                                     int M, int N, int K,
                                                     const float* __restrict__ bias,
                                                     const float* __restrict__ gmods, int g_off, int b0,
                                                     const u16* __restrict__ res, const u16* __restrict__ add,
                                                     const u16* __restrict__ uin, const float* __restrict__ Dv,
                                                     u16* __restrict__ out2) {
  __shared__ __align__(16) u16 sA[64 * 64];    // 8 KB
  __shared__ __align__(16) u16 sB[256 * 64];   // 32 KB
  const int tid = threadIdx.x;
  const int wave = tid >> 6, lane = tid & 63;
  const int m0 = blockIdx.y << 6, n0 = blockIdx.x << 8;
  const int wm = (wave >> 2) << 5;   // 0 / 32
  const int wn = (wave & 3) << 6;    // 0 / 64 / 128 / 192
  const int lr = lane & 15;
  const int lk = (lane >> 4) << 3;
  const int swz = (lr & 7) << 3;

  f32x4 acc[2][4];
#pragma unroll
  for (int i = 0; i < 2; ++i)
#pragma unroll
    for (int j = 0; j < 4; ++j) acc[i][j] = (f32x4){0.f, 0.f, 0.f, 0.f};

  const int As = (MODE == 6) ? 1024 : K;   // A row stride (cat halves are 1024 wide)
  const int gr = lane >> 3;
  const int gc = ((lane & 7) ^ gr) << 3;
  // A: 64 rows / 8 waves = 8 rows/wave = 1 gload; B: 256 rows / 8 waves = 32 rows = 4 gloads
  const u16* Ag  = A + (size_t)(m0 + wave * 8 + gr) * As + gc;
  const u16* A2g = (MODE == 6) ? (A2 + (size_t)(m0 + wave * 8 + gr) * 1024 + gc) : nullptr;
  const u16* Wg  = W + (size_t)(n0 + wave * 32 + gr) * K + gc;
  u16* lA = &sA[(wave * 8) * 64];
  u16* lB = &sB[(wave * 32) * 64];

  for (int k0 = 0; k0 < K; k0 += 64) {
    const u16* Asrc = (MODE == 6 && k0 >= 1024) ? (A2g + (k0 - 1024)) : (Ag + k0);
    __syncthreads();
    gload16(Asrc, lA);
#pragma unroll
    for (int i = 0; i < 4; ++i)
      gload16(Wg + (size_t)(i * 8) * K + k0, lB + i * 8 * 64);
    __syncthreads();
#pragma unroll
    for (int kk = 0; kk < 64; kk += 32) {
      bf16x8 af[2], bfr[4];
#pragma unroll
      for (int i = 0; i < 2; ++i)
        af[i] = *(const bf16x8*)&sA[(wm + i * 16 + lr) * 64 + ((kk + lk) ^ swz)];
#pragma unroll
      for (int j = 0; j < 4; ++j)
        bfr[j] = *(const bf16x8*)&sB[(wn + j * 16 + lr) * 64 + ((kk + lk) ^ swz)];
#pragma unroll
      for (int i = 0; i < 2; ++i)
#pragma unroll
        for (int j = 0; j < 4; ++j)
          acc[i][j] = __builtin_amdgcn_mfma_f32_16x16x32_bf16(af[i], bfr[j], acc[i][j], 0, 0, 0);
    }
  }

  const int lq = lane >> 4;
#pragma unroll
  for (int i = 0; i < 2; ++i)
#pragma unroll
    for (int j = 0; j < 4; ++j)
#pragma unroll
      for (int r = 0; r < 4; ++r) {
        int m = m0 + wm + i * 16 + lq * 4 + r;
        int n = n0 + wn + j * 16 + lr;
        float v = acc[i][j][r];
        size_t o = (size_t)m * N + n;
        if (MODE == 0) {
          out[o] = f2bf(v);
        } else if (MODE == 1) {
          float z = v + bias[n];
          out[o] = f2bf(0.5f * z * (1.0f + erff(z * 0.70710678118f)));
        } else if (MODE == 2) {
          out[o] = f2bf(v + bias[n]);
        } else if (MODE == 3) {
          out[o] = f2bf(v + bias[n] + bf2f(add[o]));
        } else if (MODE == 4) {
          out[o] = f2bf(v + bias[n] + bf2f(res[o]));
        } else if (MODE == 5) {
          int bb = b0 + (m >> 12);
          float g = gmods[bb * 3072 + g_off + n];
          out[o] = f2bf(bf2f(res[o]) + g * (v + bias[n]));
        } else {
          int bb = b0 + (m >> 12);
          float g = gmods[bb * 3072 + g_off + n];
          float c1 = g * (v + Dv[n] * bf2f(uin[o]));
          out[o] = f2bf(c1);
          if (out2) out2[o] = f2bf(bf2f(res[o]) + c1);
        }
      }
}

// ---------------------------------------------------------------- launcher
extern "C" void kernel_launch(void* const* d_in, const int* in_sizes, int n_in,
                              void* d_out, int out_size, void* d_ws, size_t ws_size,
                              hipStream_t stream) {
  (void)in_sizes; (void)n_in; (void)out_size;
  float* outp = (float*)d_out;
#define F(i) ((const float*)d_in[i])

  char* ws = (char*)d_ws;
  float*  mods  = (float*)(ws + 0x000000);
  u16*    WBp   = (u16*)(ws + 0x020000);
  u16*    WBt   = (u16*)(ws + 0x0A0000);
  u16*    WCp2  = (u16*)(ws + 0x120000);
  u16*    WCt2  = (u16*)(ws + 0x220000);
  float2* car_f = (float2*)(ws + 0x320000);
  float2* car_b = (float2*)(ws + 0x420000);
  float2* cin_f = (float2*)(ws + 0x520000);
  float2* cin_b = (float2*)(ws + 0x620000);
  u16*    wcv   = (u16*)(ws + 0x720000);   // 10 bf16 weight copies, 5 MiB

  const int widx[10] = {21, 23, 25, 27, 29, 31, 33, 35, 37, 39};
  const u16* WV[41];
  F2B10 fb;
  for (int i = 0; i < 10; ++i) {
    fb.s[i] = F(widx[i]);
    WV[widx[i]] = wcv + (size_t)i * 262144;
  }
  k_f2b10<<<dim3(1024, 10), 256, 0, stream>>>(fb, wcv);

  int nb = 1;
  for (int cand = 8; cand >= 1; cand >>= 1) {
    size_t need = (size_t)0x1000000 + (size_t)cand * 4096 * 8192;
    if (need <= ws_size) { nb = cand; break; }
  }
  const int R = nb * 4096;
  char* big = ws + 0x1000000;
  size_t sb = (size_t)R * 512;
  u16* Pt   = (u16*)(big);
  u16* Tt   = (u16*)(big + sb);
  u16* u_   = (u16*)(big + 2 * sb);
  u16* pcnd = (u16*)(big + 3 * sb);
  u16* p1   = (u16*)(big + 4 * sb);
  u16* tcb  = (u16*)(big + 5 * sb);
  u16* tmp1 = (u16*)(big + 6 * sb);
  u16* tmp2 = (u16*)(big + 7 * sb);
  u16* Bu   = (u16*)(big + 8 * sb);    // 4 sb; bwd xs rewritten in-place here
  u16* xsf  = (u16*)(big + 12 * sb);   // 4 sb; fwd xs (packed u32 slots)

  k_mods<<<dim3(12, 8), 256, 0, stream>>>(F(2), F(3), F(4), mods);
  k_wb2<<<dim3(512, 2), 256, 0, stream>>>(F(5), F(6), F(12), F(7), F(8), WBp,
                                          F(13), F(14), F(20), F(15), F(16), WBt);
  k_wc2<<<dim3(2048, 2), 256, 0, stream>>>(F(9), F(10), WCp2, F(17), F(18), WCt2);

  for (int b0 = 0; b0 < 8; b0 += nb) {
#define GEMM(MODE, Aa, Ww, Oo, Nn, Kk, biasp, goff, resp, addp)                                    \
  gemm256_bt<MODE><<<dim3((Nn) / 256, R / 64), 512, 0, stream>>>(                                  \
      (const u16*)(Aa), nullptr, (const u16*)(Ww), (u16*)(Oo), R, (Nn), (Kk),                      \
      (const float*)(biasp), mods, (goff), b0, (const u16*)(resp), (const u16*)(addp),             \
      nullptr, nullptr, nullptr)
#define SCANS2(Lr, Li, Ls)                                                                         \
  do {                                                                                             \
    k_scanA2<<<nb * 64, 256, 0, stream>>>(Lr, Li, Ls, Bu, car_f, car_b);                           \
    k_scanB2<<<dim3(nb * 2, 2), 256, 0, stream>>>(Lr, Li, Ls, car_f, car_b, cin_f, cin_b);         \
    k_scanC2<<<nb * 64, 256, 0, stream>>>(Lr, Li, Ls, Bu, cin_f, cin_b, (u32*)xsf);                \
  } while (0)
#define CAT(Ww, Oo, goff, resp, uinp, Dp, o2)                                                      \
  gemm256_bt<6><<<dim3(1, R / 64), 512, 0, stream>>>(                                              \
      (const u16*)xsf, (const u16*)Bu, (const u16*)(Ww), (u16*)(Oo), R, 256, 2048, nullptr, mods,  \
      (goff), b0, (const u16*)(resp), nullptr, (const u16*)(uinp), (const float*)(Dp), (u16*)(o2))

    k_tin2<<<dim3(64, 4, 2 * nb), dim3(64, 4), 0, stream>>>(F(0), F(1), Pt, Tt, b0, nb);

    // ---- ppg S5
    k_lnmod<<<R, 256, 0, stream>>>(Pt, u_, mods, 0 * 256, 1 * 256, b0);
    GEMM(0, u_, WBp, Bu, 1024, 256, nullptr, 0, nullptr, nullptr);
    SCANS2(F(5), F(6), F(12));
    CAT(WCp2, pcnd, 2 * 256, Pt, u_, F(11), p1);

    // ---- p-branch MLP -> output 0 (fp32)
    k_lnmod<<<R, 256, 0, stream>>>(p1, tmp1, mods, 3 * 256, 4 * 256, b0);
    GEMM(1, tmp1, WV[25], Bu, 1024, 256, F(26), 0, nullptr, nullptr);
    GEMM(5, Bu, WV[27], tmp2, 256, 1024, F(28), 5 * 256, Pt, nullptr);
    k_tout<<<dim3(64, 4, nb), dim3(64, 4), 0, stream>>>(tmp2, outp + (size_t)b0 * 1048576);

    // ---- tgt S5
    k_lnmod<<<R, 256, 0, stream>>>(Tt, u_, mods, 6 * 256, 7 * 256, b0);
    GEMM(0, u_, WBt, Bu, 1024, 256, nullptr, 0, nullptr, nullptr);
    SCANS2(F(13), F(14), F(20));
    CAT(WCt2, tcb, 8 * 256, nullptr, u_, F(19), nullptr);

    // ---- tc chain + dx -> output 1 (fp32)
    GEMM(1, pcnd, WV[21], Bu, 1024, 256, F(22), 0, nullptr, nullptr);
    GEMM(2, Bu, WV[23], tmp1, 256, 1024, F(24), 0, nullptr, nullptr);
    GEMM(1, tcb, WV[29], Bu, 1024, 256, F(30), 0, nullptr, nullptr);
    GEMM(3, Bu, WV[31], tmp2, 256, 1024, F(32), 0, nullptr, tmp1);
    GEMM(1, tmp2, WV[33], Bu, 1024, 256, F(34), 0, nullptr, nullptr);
    GEMM(4, Bu, WV[35], tcb, 256, 1024, F(36), 0, Tt, nullptr);
    k_lnmod<<<R, 256, 0, stream>>>(tcb, tmp1, mods, 9 * 256, 10 * 256, b0);
    GEMM(1, tmp1, WV[37], Bu, 1024, 256, F(38), 0, nullptr, nullptr);
    GEMM(5, Bu, WV[39], tmp2, 256, 1024, F(40), 11 * 256, Tt, nullptr);
    k_tout<<<dim3(64, 4, nb), dim3(64, 4), 0, stream>>>(tmp2, outp + 8388608 + (size_t)b0 * 1048576);

#undef GEMM
#undef SCANS2
#undef CAT
  }
#undef F
}

// Round 7
// 1085.367 us; speedup vs baseline: 1.1184x; 1.1184x over previous
//
#include <hip/hip_runtime.h>
#include <hip/hip_bf16.h>
#include <math.h>

typedef unsigned short u16;
typedef unsigned int   u32;
typedef __bf16 bf16x8 __attribute__((ext_vector_type(8)));
typedef u16    u16x8  __attribute__((ext_vector_type(8)));
typedef float  f32x4  __attribute__((ext_vector_type(4)));

#define B_  8
#define L_  4096
#define H_  256
#define P_  512
#define NC_ 32
#define CH_ 128

__device__ __forceinline__ float bf2f(u16 v) { return __uint_as_float(((u32)v) << 16); }
__device__ __forceinline__ u16 f2bf(float f) {
  u32 u = __float_as_uint(f);
  u32 r = u + 0x7FFFu + ((u >> 16) & 1u);
  return (u16)(r >> 16);
}

// async global->LDS, 16B per lane; LDS dest = wave-uniform base + lane*16
__device__ __forceinline__ void gload16(const u16* g, u16* l) {
  __builtin_amdgcn_global_load_lds((const __attribute__((address_space(1))) u32*)g,
                                   (__attribute__((address_space(3))) u32*)l, 16, 0, 0);
}

// ------------------------------------------------------- fp32 -> bf16 (x10)
struct F2B10 { const float* s[10]; };
__global__ __launch_bounds__(256) void k_f2b10(F2B10 a, u16* __restrict__ dst) {
  int g = blockIdx.y;
  int i = (blockIdx.x << 8) + threadIdx.x;
  dst[(size_t)g * 262144 + i] = f2bf(a.s[g][i]);
}

// ---------------------------------------------------------------- adaLN mods
__global__ __launch_bounds__(256) void k_mods(const float* __restrict__ cond,
                                              const float* __restrict__ wada,
                                              const float* __restrict__ bada,
                                              float* __restrict__ mods) {
  __shared__ float s[256];
  int b = blockIdx.y;
  int j = (blockIdx.x << 8) + threadIdx.x;
  float c = cond[b * 256 + threadIdx.x];
  s[threadIdx.x] = c / (1.0f + expf(-c));
  __syncthreads();
  float acc = bada[j];
  const float* wr = wada + (size_t)j * 256;
#pragma unroll 8
  for (int k = 0; k < 256; ++k) acc += s[k] * wr[k];
  mods[b * 3072 + j] = acc;
}

// ------------------------------------------------------------- transposes
__global__ __launch_bounds__(256) void k_tin2(const float* __restrict__ inP,
                                              const float* __restrict__ inT,
                                              u16* __restrict__ Pt, u16* __restrict__ Tt,
                                              int b0, int nb) {
  __shared__ u16 tile[64][65];
  int z = blockIdx.z;
  int sel = (z >= nb);
  int b = sel ? z - nb : z;
  const float* in = sel ? inT : inP;
  u16* out = sel ? Tt : Pt;
  int l0 = blockIdx.x << 6, h0 = blockIdx.y << 6;
  int tx = threadIdx.x, ty = threadIdx.y;
#pragma unroll
  for (int i = 0; i < 16; ++i) {
    int h = h0 + ty + i * 4;
    tile[ty + i * 4][tx] = f2bf(in[((size_t)(b0 + b) * 256 + h) * 4096 + l0 + tx]);
  }
  __syncthreads();
#pragma unroll
  for (int i = 0; i < 16; ++i) {
    int l = l0 + ty + i * 4;
    out[((size_t)b * 4096 + l) * 256 + h0 + tx] = tile[tx][ty + i * 4];
  }
}
__global__ __launch_bounds__(256) void k_tout(const u16* __restrict__ src, float* __restrict__ dst) {
  __shared__ u16 tile[64][65];
  int b = blockIdx.z, l0 = blockIdx.x << 6, h0 = blockIdx.y << 6;
  int tx = threadIdx.x, ty = threadIdx.y;
#pragma unroll
  for (int i = 0; i < 16; ++i) {
    int l = l0 + ty + i * 4;
    tile[ty + i * 4][tx] = src[((size_t)b * 4096 + l) * 256 + h0 + tx];
  }
  __syncthreads();
#pragma unroll
  for (int i = 0; i < 16; ++i) {
    int h = h0 + ty + i * 4;
    dst[((size_t)b * 256 + h) * 4096 + l0 + tx] = bf2f(tile[tx][ty + i * 4]);
  }
}

// ------------------------------------------------------------- LN + adaLN mod
__global__ __launch_bounds__(256) void k_lnmod(const u16* __restrict__ X, u16* __restrict__ U,
                                               const float* __restrict__ mods,
                                               int sh_off, int sc_off, int b0) {
  int t = blockIdx.x, tid = threadIdx.x;
  int b = b0 + (t >> 12);
  float x = bf2f(X[(size_t)t * 256 + tid]);
  float s1 = x, s2 = x * x;
#pragma unroll
  for (int off = 32; off; off >>= 1) { s1 += __shfl_xor(s1, off); s2 += __shfl_xor(s2, off); }
  __shared__ float red[8];
  int w = tid >> 6;
  if ((tid & 63) == 0) { red[w * 2] = s1; red[w * 2 + 1] = s2; }
  __syncthreads();
  s1 = red[0] + red[2] + red[4] + red[6];
  s2 = red[1] + red[3] + red[5] + red[7];
  float m = s1 * (1.0f / 256.0f);
  float v = fmaxf(s2 * (1.0f / 256.0f) - m * m, 0.0f);
  float r = rsqrtf(v + 1e-6f);
  float sc = mods[b * 3072 + sc_off + tid];
  float sh = mods[b * 3072 + sh_off + tid];
  U[(size_t)t * 256 + tid] = f2bf((x - m) * r * (1.0f + sc) + sh);
}

// ------------------------------------------------------------- S5 weight prep
__global__ __launch_bounds__(256) void k_wb2(const float* Lre0, const float* Lim0, const float* ls0,
                                             const float* Bre0, const float* Bim0, u16* WB0,
                                             const float* Lre1, const float* Lim1, const float* ls1,
                                             const float* Bre1, const float* Bim1, u16* WB1) {
  int s = blockIdx.y;
  const float* Lre = s ? Lre1 : Lre0;
  const float* Lim = s ? Lim1 : Lim0;
  const float* ls  = s ? ls1  : ls0;
  const float* Bre = s ? Bre1 : Bre0;
  const float* Bim = s ? Bim1 : Bim0;
  u16* WB = s ? WB1 : WB0;
  int p = blockIdx.x, h = threadIdx.x;
  float lre = Lre[p], lim = Lim[p];
  float dt = expf(ls[p]);
  float er = expf(lre * dt), sn, cs;
  sincosf(lim * dt, &sn, &cs);
  float ar = er * cs - 1.0f, ai = er * sn;
  float den = lre * lre + lim * lim;
  float cr = (ar * lre + ai * lim) / den;
  float ci = (ai * lre - ar * lim) / den;
  float br = Bre[p * 256 + h], bi = Bim[p * 256 + h];
  WB[(size_t)(2 * p) * 256 + h]     = f2bf(cr * br - ci * bi);
  WB[(size_t)(2 * p + 1) * 256 + h] = f2bf(cr * bi + ci * br);
}

// interleaved concat C-weight: K=2048, even k -> 2*Cre, odd -> -2*Cim
__global__ __launch_bounds__(256) void k_wc2(const float* Cre0, const float* Cim0, u16* W0,
                                             const float* Cre1, const float* Cim1, u16* W1) {
  int s = blockIdx.y;
  const float* Cre = s ? Cre1 : Cre0;
  const float* Cim = s ? Cim1 : Cim0;
  u16* W = s ? W1 : W0;
  int idx = (blockIdx.x << 8) + threadIdx.x;
  int h = idx >> 11, k = idx & 2047;
  int sc = ((k >> 10) << 9) + ((k & 1023) >> 1);
  float v = (k & 1) ? -2.0f * Cim[h * 1024 + sc] : 2.0f * Cre[h * 1024 + sc];
  W[idx] = f2bf(v);
}

// ------------------------------------------------------------- fused scans
__device__ __forceinline__ float2 lbar_of(const float* Lre, const float* Lim, const float* lstep,
                                          int p, float mul) {
  float dt = expf(lstep[p]) * mul;
  float er = expf(Lre[p] * dt), sn, cs;
  sincosf(Lim[p] * dt, &sn, &cs);
  return make_float2(er * cs, er * sn);
}

// one read of Bu -> BOTH direction chunk-carries
__global__ __launch_bounds__(256) void k_scanA2(const float* Lre, const float* Lim, const float* lstep,
                                                const u16* __restrict__ Bu,
                                                float2* __restrict__ car_f, float2* __restrict__ car_b) {
  int g = (blockIdx.x << 8) + threadIdx.x;
  int p = g & 511, rb = (g >> 9) & 31, bl = g >> 14;
  float2 a = lbar_of(Lre, Lim, lstep, p, 1.0f);
  float fr = 0.f, fi = 0.f;
  float br_ = 0.f, bi_ = 0.f;
  float pr = 1.f, pi = 0.f;
  const u32* bup = (const u32*)Bu + (((size_t)((bl << 12) + rb * CH_)) << 9) + p;
#pragma unroll 4
  for (int j = 0; j < CH_; ++j) {
    u32 w = *bup;
    float er = bf2f((u16)(w & 0xFFFF)), ei = bf2f((u16)(w >> 16));
    float nr = a.x * fr - a.y * fi + er;
    float ni = a.x * fi + a.y * fr + ei;
    fr = nr; fi = ni;
    br_ += pr * er - pi * ei;
    bi_ += pr * ei + pi * er;
    float npr = pr * a.x - pi * a.y;
    float npi = pr * a.y + pi * a.x;
    pr = npr; pi = npi;
    bup += 512;
  }
  car_f[g] = make_float2(fr, fi);
  car_b[((size_t)bl << 14) + ((size_t)(31 - rb) << 9) + p] = make_float2(br_, bi_);
}

__global__ __launch_bounds__(256) void k_scanB2(const float* Lre, const float* Lim, const float* lstep,
                                                const float2* __restrict__ car_f,
                                                const float2* __restrict__ car_b,
                                                float2* __restrict__ cin_f, float2* __restrict__ cin_b) {
  int dir = blockIdx.y;
  int g = (blockIdx.x << 8) + threadIdx.x;
  int p = g & 511, bl = g >> 9;
  float2 an = lbar_of(Lre, Lim, lstep, p, (float)CH_);
  const float2* car = dir ? car_b : car_f;
  float2* cin = dir ? cin_b : cin_f;
  float xr = 0.f, xi = 0.f;
  size_t base = (size_t)bl * 16384 + p;
  for (int c = 0; c < NC_; ++c) {
    size_t src = base + (size_t)c * 512;
    size_t dst = dir ? (base + (size_t)(31 - c) * 512) : src;
    cin[dst] = make_float2(xr, xi);
    float2 E = car[src];
    float nr = an.x * xr - an.y * xi + E.x;
    float ni = an.x * xi + an.y * xr + E.y;
    xr = nr; xi = ni;
  }
}

// fwd pass: write packed xs -> xsf. bwd pass: overwrite Bu in place (race-free per thread).
__global__ __launch_bounds__(256) void k_scanC2(const float* Lre, const float* Lim, const float* lstep,
                                                u16* __restrict__ Bu,
                                                const float2* __restrict__ cin_f,
                                                const float2* __restrict__ cin_b,
                                                u32* __restrict__ xsf) {
  int g = (blockIdx.x << 8) + threadIdx.x;
  int p = g & 511, rb = (g >> 9) & 31, bl = g >> 14;
  float2 a = lbar_of(Lre, Lim, lstep, p, 1.0f);
  size_t rowbase = (((size_t)((bl << 12) + rb * CH_)) << 9) + p;
  const u32* bup = (const u32*)Bu + rowbase;
  u32* xop = xsf + rowbase;
  float2 c0 = cin_f[g];
  float xr = c0.x, xi = c0.y;
#pragma unroll 4
  for (int j = 0; j < CH_; ++j) {
    u32 w = *bup;
    float er = bf2f((u16)(w & 0xFFFF)), ei = bf2f((u16)(w >> 16));
    float nr = a.x * xr - a.y * xi + er;
    float ni = a.x * xi + a.y * xr + ei;
    xr = nr; xi = ni;
    *xop = (u32)f2bf(xr) | ((u32)f2bf(xi) << 16);
    bup += 512; xop += 512;
  }
  u32* bwp = (u32*)Bu + rowbase + ((size_t)(CH_ - 1) << 9);
  c0 = cin_b[g];
  xr = c0.x; xi = c0.y;
#pragma unroll 4
  for (int j = 0; j < CH_; ++j) {
    u32 w = *bwp;
    float er = bf2f((u16)(w & 0xFFFF)), ei = bf2f((u16)(w >> 16));
    float nr = a.x * xr - a.y * xi + er;
    float ni = a.x * xi + a.y * xr + ei;
    xr = nr; xi = ni;
    *bwp = (u32)f2bf(xr) | ((u32)f2bf(xi) << 16);
    bwp -= 512;
  }
}

// ------------------------------------------------------------- MFMA GEMM
// 64x64 tile, 16 KB LDS, launch_bounds(256,8) -> 8 blocks/CU = 32 waves/CU.
// Proven fastest structure for these shapes (rounds 3-6 A/B: occupancy beats traffic).
// Chunked XCD swizzle (T1): physical block b runs work (b%8)*cpx + b/8, so the
// n-group of blocks sharing one A row-block is consecutive on ONE XCD -> the
// n-fold A re-read is served by that XCD's L2 (A-block = 128 KB, L2-resident)
// instead of L3/HBM. Bijective since grid total % 8 == 0 for all our shapes.
// Both-sides XOR swizzle on LDS (rule #21) keeps SQ_LDS_BANK_CONFLICT = 0.
// MODE 0: bf16 store   1: gelu(acc+bias)   2: acc+bias   3: acc+bias+add
// MODE 4: acc+bias+res 5: res+g*(acc+bias) 6: cat S5 proj (A|A2, K=2048, As=1024)
template <int MODE>
__global__ __launch_bounds__(256, 8) void gemm64s_bt(const u16* __restrict__ A, const u16* __restrict__ A2,
                                                     const u16* __restrict__ W, u16* __restrict__ out,
                                                     int M, int N, int K,
                                                     const float* __restrict__ bias,
                                                     const float* __restrict__ gmods, int g_off, int b0,
                                                     const u16* __restrict__ res, const u16* __restrict__ add,
                                                     const u16* __restrict__ uin, const float* __restrict__ Dv,
                                                     u16* __restrict__ out2) {
  __shared__ __align__(16) u16 sA[64 * 64];
  __shared__ __align__(16) u16 sB[64 * 64];
  const int tid = threadIdx.x;
  const int wave = tid >> 6, lane = tid & 63;

  // chunked XCD swizzle: work id = (b%8)*cpx + b/8; bx fastest (n), by = m
  const int nx = gridDim.x;
  const int tot = nx * gridDim.y;
  const int bid = blockIdx.x + nx * blockIdx.y;
  const int wid = (bid & 7) * (tot >> 3) + (bid >> 3);
  const int nxs = 31 - __clz(nx);          // nx is a power of two (4/8/16)
  const int m0 = (wid >> nxs) << 6;
  const int n0 = (wid & (nx - 1)) << 6;

  const int wm = (wave >> 1) << 5, wn = (wave & 1) << 5;
  const int lr = lane & 15;
  const int lk = (lane >> 4) << 3;
  const int swz = (lr & 7) << 3;

  f32x4 acc[2][2];
#pragma unroll
  for (int i = 0; i < 2; ++i)
#pragma unroll
    for (int j = 0; j < 2; ++j) acc[i][j] = (f32x4){0.f, 0.f, 0.f, 0.f};

  const int As = (MODE == 6) ? 1024 : K;   // A row stride (cat halves are 1024 wide)
  const int gr = lane >> 3;
  const int gc = ((lane & 7) ^ gr) << 3;
  const u16* Ag  = A + (size_t)(m0 + wave * 16 + gr) * As + gc;
  const u16* A2g = (MODE == 6) ? (A2 + (size_t)(m0 + wave * 16 + gr) * 1024 + gc) : nullptr;
  const u16* Wg  = W + (size_t)(n0 + wave * 16 + gr) * K + gc;
  u16* lA = &sA[(wave * 16) * 64];
  u16* lB = &sB[(wave * 16) * 64];

  for (int k0 = 0; k0 < K; k0 += 64) {
    const u16* Asrc = (MODE == 6 && k0 >= 1024) ? (A2g + (k0 - 1024)) : (Ag + k0);
    __syncthreads();
    gload16(Asrc, lA);
    gload16(Asrc + (size_t)8 * As, lA + 8 * 64);
    gload16(Wg + k0, lB);
    gload16(Wg + (size_t)8 * K + k0, lB + 8 * 64);
    __syncthreads();
#pragma unroll
    for (int kk = 0; kk < 64; kk += 32) {
      bf16x8 af[2], bfr[2];
#pragma unroll
      for (int i = 0; i < 2; ++i)
        af[i] = *(const bf16x8*)&sA[(wm + i * 16 + lr) * 64 + ((kk + lk) ^ swz)];
#pragma unroll
      for (int j = 0; j < 2; ++j)
        bfr[j] = *(const bf16x8*)&sB[(wn + j * 16 + lr) * 64 + ((kk + lk) ^ swz)];
#pragma unroll
      for (int i = 0; i < 2; ++i)
#pragma unroll
        for (int j = 0; j < 2; ++j)
          acc[i][j] = __builtin_amdgcn_mfma_f32_16x16x32_bf16(af[i], bfr[j], acc[i][j], 0, 0, 0);
    }
  }

  const int lq = lane >> 4;
#pragma unroll
  for (int i = 0; i < 2; ++i)
#pragma unroll
    for (int j = 0; j < 2; ++j)
#pragma unroll
      for (int r = 0; r < 4; ++r) {
        int m = m0 + wm + i * 16 + lq * 4 + r;
        int n = n0 + wn + j * 16 + lr;
        float v = acc[i][j][r];
        size_t o = (size_t)m * N + n;
        if (MODE == 0) {
          out[o] = f2bf(v);
        } else if (MODE == 1) {
          float z = v + bias[n];
          out[o] = f2bf(0.5f * z * (1.0f + erff(z * 0.70710678118f)));
        } else if (MODE == 2) {
          out[o] = f2bf(v + bias[n]);
        } else if (MODE == 3) {
          out[o] = f2bf(v + bias[n] + bf2f(add[o]));
        } else if (MODE == 4) {
          out[o] = f2bf(v + bias[n] + bf2f(res[o]));
        } else if (MODE == 5) {
          int bb = b0 + (m >> 12);
          float g = gmods[bb * 3072 + g_off + n];
          out[o] = f2bf(bf2f(res[o]) + g * (v + bias[n]));
        } else {
          int bb = b0 + (m >> 12);
          float g = gmods[bb * 3072 + g_off + n];
          float c1 = g * (v + Dv[n] * bf2f(uin[o]));
          out[o] = f2bf(c1);
          if (out2) out2[o] = f2bf(bf2f(res[o]) + c1);
        }
      }
}

// ---------------------------------------------------------------- launcher
extern "C" void kernel_launch(void* const* d_in, const int* in_sizes, int n_in,
                              void* d_out, int out_size, void* d_ws, size_t ws_size,
                              hipStream_t stream) {
  (void)in_sizes; (void)n_in; (void)out_size;
  float* outp = (float*)d_out;
#define F(i) ((const float*)d_in[i])

  char* ws = (char*)d_ws;
  float*  mods  = (float*)(ws + 0x000000);
  u16*    WBp   = (u16*)(ws + 0x020000);
  u16*    WBt   = (u16*)(ws + 0x0A0000);
  u16*    WCp2  = (u16*)(ws + 0x120000);
  u16*    WCt2  = (u16*)(ws + 0x220000);
  float2* car_f = (float2*)(ws + 0x320000);
  float2* car_b = (float2*)(ws + 0x420000);
  float2* cin_f = (float2*)(ws + 0x520000);
  float2* cin_b = (float2*)(ws + 0x620000);
  u16*    wcv   = (u16*)(ws + 0x720000);   // 10 bf16 weight copies, 5 MiB

  const int widx[10] = {21, 23, 25, 27, 29, 31, 33, 35, 37, 39};
  const u16* WV[41];
  F2B10 fb;
  for (int i = 0; i < 10; ++i) {
    fb.s[i] = F(widx[i]);
    WV[widx[i]] = wcv + (size_t)i * 262144;
  }
  k_f2b10<<<dim3(1024, 10), 256, 0, stream>>>(fb, wcv);

  int nb = 1;
  for (int cand = 8; cand >= 1; cand >>= 1) {
    size_t need = (size_t)0x1000000 + (size_t)cand * 4096 * 8192;
    if (need <= ws_size) { nb = cand; break; }
  }
  const int R = nb * 4096;
  char* big = ws + 0x1000000;
  size_t sb = (size_t)R * 512;
  u16* Pt   = (u16*)(big);
  u16* Tt   = (u16*)(big + sb);
  u16* u_   = (u16*)(big + 2 * sb);
  u16* pcnd = (u16*)(big + 3 * sb);
  u16* p1   = (u16*)(big + 4 * sb);
  u16* tcb  = (u16*)(big + 5 * sb);
  u16* tmp1 = (u16*)(big + 6 * sb);
  u16* tmp2 = (u16*)(big + 7 * sb);
  u16* Bu   = (u16*)(big + 8 * sb);    // 4 sb; bwd xs rewritten in-place here
  u16* xsf  = (u16*)(big + 12 * sb);   // 4 sb; fwd xs (packed u32 slots)

  k_mods<<<dim3(12, 8), 256, 0, stream>>>(F(2), F(3), F(4), mods);
  k_wb2<<<dim3(512, 2), 256, 0, stream>>>(F(5), F(6), F(12), F(7), F(8), WBp,
                                          F(13), F(14), F(20), F(15), F(16), WBt);
  k_wc2<<<dim3(2048, 2), 256, 0, stream>>>(F(9), F(10), WCp2, F(17), F(18), WCt2);

  for (int b0 = 0; b0 < 8; b0 += nb) {
#define GEMM(MODE, Aa, Ww, Oo, Nn, Kk, biasp, goff, resp, addp)                                    \
  gemm64s_bt<MODE><<<dim3((Nn) / 64, R / 64), 256, 0, stream>>>(                                   \
      (const u16*)(Aa), nullptr, (const u16*)(Ww), (u16*)(Oo), R, (Nn), (Kk),                      \
      (const float*)(biasp), mods, (goff), b0, (const u16*)(resp), (const u16*)(addp),             \
      nullptr, nullptr, nullptr)
#define SCANS2(Lr, Li, Ls)                                                                         \
  do {                                                                                             \
    k_scanA2<<<nb * 64, 256, 0, stream>>>(Lr, Li, Ls, Bu, car_f, car_b);                           \
    k_scanB2<<<dim3(nb * 2, 2), 256, 0, stream>>>(Lr, Li, Ls, car_f, car_b, cin_f, cin_b);         \
    k_scanC2<<<nb * 64, 256, 0, stream>>>(Lr, Li, Ls, Bu, cin_f, cin_b, (u32*)xsf);                \
  } while (0)
#define CAT(Ww, Oo, goff, resp, uinp, Dp, o2)                                                      \
  gemm64s_bt<6><<<dim3(4, R / 64), 256, 0, stream>>>(                                              \
      (const u16*)xsf, (const u16*)Bu, (const u16*)(Ww), (u16*)(Oo), R, 256, 2048, nullptr, mods,  \
      (goff), b0, (const u16*)(resp), nullptr, (const u16*)(uinp), (const float*)(Dp), (u16*)(o2))

    k_tin2<<<dim3(64, 4, 2 * nb), dim3(64, 4), 0, stream>>>(F(0), F(1), Pt, Tt, b0, nb);

    // ---- ppg S5
    k_lnmod<<<R, 256, 0, stream>>>(Pt, u_, mods, 0 * 256, 1 * 256, b0);
    GEMM(0, u_, WBp, Bu, 1024, 256, nullptr, 0, nullptr, nullptr);
    SCANS2(F(5), F(6), F(12));
    CAT(WCp2, pcnd, 2 * 256, Pt, u_, F(11), p1);

    // ---- p-branch MLP -> output 0 (fp32)
    k_lnmod<<<R, 256, 0, stream>>>(p1, tmp1, mods, 3 * 256, 4 * 256, b0);
    GEMM(1, tmp1, WV[25], Bu, 1024, 256, F(26), 0, nullptr, nullptr);
    GEMM(5, Bu, WV[27], tmp2, 256, 1024, F(28), 5 * 256, Pt, nullptr);
    k_tout<<<dim3(64, 4, nb), dim3(64, 4), 0, stream>>>(tmp2, outp + (size_t)b0 * 1048576);

    // ---- tgt S5
    k_lnmod<<<R, 256, 0, stream>>>(Tt, u_, mods, 6 * 256, 7 * 256, b0);
    GEMM(0, u_, WBt, Bu, 1024, 256, nullptr, 0, nullptr, nullptr);
    SCANS2(F(13), F(14), F(20));
    CAT(WCt2, tcb, 8 * 256, nullptr, u_, F(19), nullptr);

    // ---- tc chain + dx -> output 1 (fp32)
    GEMM(1, pcnd, WV[21], Bu, 1024, 256, F(22), 0, nullptr, nullptr);
    GEMM(2, Bu, WV[23], tmp1, 256, 1024, F(24), 0, nullptr, nullptr);
    GEMM(1, tcb, WV[29], Bu, 1024, 256, F(30), 0, nullptr, nullptr);
    GEMM(3, Bu, WV[31], tmp2, 256, 1024, F(32), 0, nullptr, tmp1);
    GEMM(1, tmp2, WV[33], Bu, 1024, 256, F(34), 0, nullptr, nullptr);
    GEMM(4, Bu, WV[35], tcb, 256, 1024, F(36), 0, Tt, nullptr);
    k_lnmod<<<R, 256, 0, stream>>>(tcb, tmp1, mods, 9 * 256, 10 * 256, b0);
    GEMM(1, tmp1, WV[37], Bu, 1024, 256, F(38), 0, nullptr, nullptr);
    GEMM(5, Bu, WV[39], tmp2, 256, 1024, F(40), 11 * 256, Tt, nullptr);
    k_tout<<<dim3(64, 4, nb), dim3(64, 4), 0, stream>>>(tmp2, outp + 8388608 + (size_t)b0 * 1048576);

#undef GEMM
#undef SCANS2
#undef CAT
  }
#undef F
}